// Round 4
// baseline (92.851 us; speedup 1.0000x reference)
//
#include <hip/hip_runtime.h>

// Problem constants (B=2, H=4 -> NBH=8; Tq=Tk=512; D=64; HID=128)
#define T    512
#define D    64
#define HID  128
#define NBH  8
#define NP   (HID / 2)   // 64 c-pairs

typedef _Float16 h2 __attribute__((ext_vector_type(2)));

static __device__ __forceinline__ h2 bc_h2(float f) {
    return __builtin_bit_cast(h2, f);
}

// Guaranteed single v_pk_max_f16 (relu on a packed f16 pair).
// __builtin_elementwise_max may scalarize into 2x v_max_f16.
static __device__ __forceinline__ h2 relu_h2(h2 x) {
    h2 r;
    asm("v_pk_max_f16 %0, %1, 0" : "=v"(r) : "v"(x));
    return r;
}

// ---------------------------------------------------------------------------
// Phase A: qh[bh][c][i] = b1[c] + sum_d q[bh][i][d] * W1[d][c]   (src==0)
//          kh[bh][c][j] =         sum_d k[bh][j][d] * W1[64+d][c] (src==1)
// Output packed as h2 pairs over c: ws[bh][p][i], i contiguous.
// grid: 8 bh x 2 src x 8 row-chunks x 4 c-splits = 512 blocks (2/CU).
// ---------------------------------------------------------------------------
__global__ __launch_bounds__(256, 2) void proj_kernel(
    const float* __restrict__ q, const float* __restrict__ k,
    const float* __restrict__ W1, const float* __restrict__ b1,
    h2* __restrict__ qh_h, h2* __restrict__ kh_h)
{
    const int bid    = blockIdx.x;        // [0,512)
    const int bh     = bid >> 6;
    const int src    = (bid >> 5) & 1;
    const int chunk  = (bid >> 2) & 7;
    const int csplit = bid & 3;
    const int base_c = csplit * 32;       // 32 channels per block

    const float* __restrict__ X = (src == 0) ? q : k;
    h2* __restrict__ outp       = (src == 0) ? qh_h : kh_h;

    // 32 c-rows of W1, transposed to [cc][d]; stride 68 floats keeps 16 B
    // alignment (272 B) and breaks pow-2 bank stride on staging writes.
    __shared__ float w1t[32][68];

    const int tid = threadIdx.x;
    for (int idx = tid; idx < 32 * 64; idx += 256) {
        const int cc = idx & 31;          // consecutive -> coalesced global read
        const int d  = idx >> 5;
        w1t[cc][d] = W1[(src * D + d) * HID + base_c + cc];
    }
    __syncthreads();

    const int r  = tid & 63;              // lane -> row (stores coalesce)
    const int cg = tid >> 6;              // wave -> 8-c group (wave-uniform)
    const int i  = chunk * 64 + r;

    // This thread's input row in registers (64 VGPR).
    float xr[D];
    const float4* xrow = (const float4*)(X + (size_t)(bh * T + i) * D);
    #pragma unroll
    for (int t = 0; t < D / 4; ++t) {
        const float4 v = xrow[t];
        xr[4*t+0] = v.x; xr[4*t+1] = v.y; xr[4*t+2] = v.z; xr[4*t+3] = v.w;
    }

    #pragma unroll
    for (int pp = 0; pp < 4; ++pp) {
        const int cc0 = cg * 8 + 2 * pp;         // wave-uniform -> LDS broadcast
        float acc0 = (src == 0) ? b1[base_c + cc0]     : 0.0f;
        float acc1 = (src == 0) ? b1[base_c + cc0 + 1] : 0.0f;
        const float4* w0 = (const float4*)(&w1t[cc0][0]);
        const float4* w1 = (const float4*)(&w1t[cc0 + 1][0]);
        #pragma unroll
        for (int t = 0; t < D / 4; ++t) {
            const float4 a = w0[t];
            const float4 b = w1[t];
            acc0 += xr[4*t+0]*a.x + xr[4*t+1]*a.y + xr[4*t+2]*a.z + xr[4*t+3]*a.w;
            acc1 += xr[4*t+0]*b.x + xr[4*t+1]*b.y + xr[4*t+2]*b.z + xr[4*t+3]*b.w;
        }
        h2 v;
        v.x = (_Float16)acc0;
        v.y = (_Float16)acc1;
        const int p = csplit * 16 + cg * 4 + pp;  // global pair index [0,64)
        outp[(size_t)(bh * NP + p) * T + i] = v;  // lanes span i -> coalesced
    }
}

// ---------------------------------------------------------------------------
// Phase B: s[bh][i][j] = b2 + sum_c W2[c] * relu(qh[bh][c][i] + kh[bh][c][j])
// 64x32 output tile, 256 threads, 4x2 fp32 acc/thread.
// Occupancy experiment: grid 1024 (4 blocks/CU), LDS 24.5 KB, lb(256,4)
// -> 16 waves/CU (R3 had 8). Inner: per c-pair per cell: v_pk_add_f16 +
// v_pk_max_f16 (inline asm) + v_dot2_f32_f16 = 3 VALU / 2 MACs.
// K-fragment reads: 16 distinct 8 B addrs -> even banks 0..30, conflict-free.
// grid: 8 bh x 8 it x 16 jt = 1024 blocks.
// ---------------------------------------------------------------------------
__global__ __launch_bounds__(256, 4) void score_kernel(
    const h2* __restrict__ qh_h, const h2* __restrict__ kh_h,
    const float* __restrict__ W2, const float* __restrict__ b2,
    float* __restrict__ out)
{
    const int bid = blockIdx.x;           // [0, 1024)
    const int bh  = bid >> 7;
    const int it  = (bid >> 4) & 7;
    const int jt  = bid & 15;
    const int i0  = it * 64;
    const int j0  = jt * 32;

    __shared__ h2 qt2[NP][64];            // 16 KB, row = 256 B (16 float4)
    __shared__ h2 kt2[NP][32];            // 8 KB,  row = 128 B (8 float4)
    __shared__ h2 w2h[NP];                // 256 B

    const int tid = threadIdx.x;
    // Stage tiles: 1024 q-float4 + 512 k-float4 = 6 per thread, coalesced rows.
    for (int idx = tid; idx < 1536; idx += 256) {
        if (idx < 1024) {
            const int p = idx >> 4;
            const int g = idx & 15;
            ((float4*)&qt2[p][0])[g] =
                ((const float4*)(qh_h + (size_t)(bh * NP + p) * T + i0))[g];
        } else {
            const int r = idx - 1024;
            const int p = r >> 3;
            const int g = r & 7;
            ((float4*)&kt2[p][0])[g] =
                ((const float4*)(kh_h + (size_t)(bh * NP + p) * T + j0))[g];
        }
    }
    if (tid < NP) {
        h2 w;
        w.x = (_Float16)W2[2 * tid];
        w.y = (_Float16)W2[2 * tid + 1];
        w2h[tid] = w;
    }
    __syncthreads();

    const int tx = tid & 15;              // j pair: j = j0 + 2*tx
    const int ty = tid >> 4;              // i quad: i = i0 + 4*ty

    float acc[4][2];
    #pragma unroll
    for (int m = 0; m < 4; ++m) {
        acc[m][0] = 0.0f;
        acc[m][1] = 0.0f;
    }

    #pragma unroll 8
    for (int p = 0; p < NP; ++p) {
        const float4 qa4 = ((const float4*)&qt2[p][0])[ty];  // 4 h2: i..i+3
        const float2 kb2 = ((const float2*)&kt2[p][0])[tx];  // 2 h2: j, j+1
        const h2 w = w2h[p];
        const h2 qv[4] = {bc_h2(qa4.x), bc_h2(qa4.y), bc_h2(qa4.z), bc_h2(qa4.w)};
        const h2 kv[2] = {bc_h2(kb2.x), bc_h2(kb2.y)};
        #pragma unroll
        for (int m = 0; m < 4; ++m) {
            #pragma unroll
            for (int n = 0; n < 2; ++n) {
                h2 u = qv[m] + kv[n];                 // v_pk_add_f16
                u = relu_h2(u);                       // v_pk_max_f16 (asm)
                acc[m][n] = __builtin_amdgcn_fdot2(u, w, acc[m][n], false);
            }
        }
    }

    const float bb = b2[0];
    #pragma unroll
    for (int m = 0; m < 4; ++m) {
        const int i = i0 + 4 * ty + m;
        float2 o;
        o.x = acc[m][0] + bb;
        o.y = acc[m][1] + bb;
        // 16 lanes x 8 B contiguous per (ty,m) sub-row.
        ((float2*)(out + (size_t)(bh * T + i) * T + j0))[tx] = o;
    }
}

extern "C" void kernel_launch(void* const* d_in, const int* in_sizes, int n_in,
                              void* d_out, int out_size, void* d_ws, size_t ws_size,
                              hipStream_t stream) {
    const float* q  = (const float*)d_in[0];
    const float* k  = (const float*)d_in[1];
    const float* W1 = (const float*)d_in[2];
    const float* b1 = (const float*)d_in[3];
    const float* W2 = (const float*)d_in[4];
    const float* b2 = (const float*)d_in[5];
    float* out = (float*)d_out;

    // Workspace: qh_h + kh_h as h2 pairs, each 8*64*512*4 B = 1 MB.
    h2* qh_h = (h2*)d_ws;
    h2* kh_h = qh_h + (size_t)NBH * NP * T;

    proj_kernel<<<512, 256, 0, stream>>>(q, k, W1, b1, qh_h, kh_h);
    score_kernel<<<1024, 256, 0, stream>>>(qh_h, kh_h, W2, b2, out);
}